// Round 2
// baseline (1792.949 us; speedup 1.0000x reference)
//
#include <hip/hip_runtime.h>
#include <hip/hip_fp16.h>
#include <math.h>

#define T_LEN 1024
#define BATCH 512
#define DIN   12
#define HID   100
#define G4    400
#define PK    52      // half2 pairs per column (104 halves, padded)
#define NCH   13      // 16B chunks per (batch) h vector

typedef _Float16 half2_t __attribute__((ext_vector_type(2)));

__device__ __forceinline__ float fast_exp2(float x) {
#if __has_builtin(__builtin_amdgcn_exp2f)
    return __builtin_amdgcn_exp2f(x);
#else
    return exp2f(x);
#endif
}
__device__ __forceinline__ float fast_rcp(float x) {
#if __has_builtin(__builtin_amdgcn_rcpf)
    return __builtin_amdgcn_rcpf(x);
#else
    return 1.0f / x;
#endif
}

__device__ __forceinline__ float dot2p(unsigned int hpair, unsigned int wpair, float acc) {
#if __has_builtin(__builtin_amdgcn_fdot2)
    return __builtin_amdgcn_fdot2(__builtin_bit_cast(half2_t, hpair),
                                  __builtin_bit_cast(half2_t, wpair), acc, false);
#else
    half2_t h = __builtin_bit_cast(half2_t, hpair);
    half2_t w = __builtin_bit_cast(half2_t, wpair);
    return acc + (float)h[0] * (float)w[0] + (float)h[1] * (float)w[1];
#endif
}

__device__ __forceinline__ unsigned int pack_pair(float a, float b) {
    half2_t p;
    p[0] = (_Float16)a;
    p[1] = (_Float16)b;
    return __builtin_bit_cast(unsigned int, p);
}

// block = 256 (4 waves, 1/SIMD), grid = 256 (1 block/CU), 2 batches per block.
// Threads 0-199: 2 gate-columns each (cols 2t, 2t+1), both batches.
// Threads 200-211: output-projection column d=tid-200, both batches.
// Threads 212-255: dummy (zero weights).
// Phase B (cell update): threads 0-199.
__launch_bounds__(256, 1)
__global__ void lstm_fused_kernel(const float* __restrict__ x,
                                  const float* __restrict__ Wx,
                                  const float* __restrict__ Wh,
                                  const float* __restrict__ b,
                                  const float* __restrict__ Wd,
                                  const float* __restrict__ bd,
                                  float* __restrict__ out) {
    const int tid = threadIdx.x;
    const int b0  = blockIdx.x * 2;

    // h as fp16, padded to 104 per (parity, batch); rows are 208B = 13x16B aligned.
    __shared__ __align__(16) __half hbuf[2][2][8 * NCH];
    __shared__ __align__(16) float  za[2][G4];

    const bool is_mm = (tid < 200);
    const bool is_pj = (tid >= 200) && (tid < 212);

    unsigned int wA[PK], wB[PK];
    float wxA[DIN], wxB[DIN];
    float biasA = 0.f, biasB = 0.f;
    bool  gA = false, gB = false;      // tanh gate flag per column
    int   cA = 0, cB = 0, pd = 0;

    if (is_mm) {
        cA = 2 * tid;
        cB = 2 * tid + 1;
        gA = (cA >= 2 * HID) && (cA < 3 * HID);
        gB = (cB >= 2 * HID) && (cB < 3 * HID);
#pragma unroll
        for (int p = 0; p < PK; ++p) {
            const int k0 = 2 * p, k1 = 2 * p + 1;
            const float a0 = (k0 < HID) ? Wh[k0 * G4 + cA] : 0.f;
            const float a1 = (k1 < HID) ? Wh[k1 * G4 + cA] : 0.f;
            const float b0f = (k0 < HID) ? Wh[k0 * G4 + cB] : 0.f;
            const float b1f = (k1 < HID) ? Wh[k1 * G4 + cB] : 0.f;
            wA[p] = pack_pair(a0, a1);
            wB[p] = pack_pair(b0f, b1f);
        }
#pragma unroll
        for (int d = 0; d < DIN; ++d) {
            wxA[d] = Wx[d * G4 + cA];
            wxB[d] = Wx[d * G4 + cB];
        }
        biasA = b[cA];
        biasB = b[cB];
    } else if (is_pj) {
        pd = tid - 200;
#pragma unroll
        for (int p = 0; p < PK; ++p) {
            const int k0 = 2 * p, k1 = 2 * p + 1;
            const float a0 = (k0 < HID) ? Wd[k0 * DIN + pd] : 0.f;
            const float a1 = (k1 < HID) ? Wd[k1 * DIN + pd] : 0.f;
            wA[p] = pack_pair(a0, a1);
            wB[p] = 0u;
        }
#pragma unroll
        for (int d = 0; d < DIN; ++d) { wxA[d] = 0.f; wxB[d] = 0.f; }
        biasA = bd[pd];
        biasB = 0.f;
    } else {
#pragma unroll
        for (int p = 0; p < PK; ++p) { wA[p] = 0u; wB[p] = 0u; }
#pragma unroll
        for (int d = 0; d < DIN; ++d) { wxA[d] = 0.f; wxB[d] = 0.f; }
    }

    // zero-init hbuf (both parities; pads must stay zero)
    if (tid < 2 * 2 * NCH) {
        ((uint4*)hbuf)[tid] = make_uint4(0u, 0u, 0u, 0u);
    }
    float c = 0.f;   // cell state for update threads (tid < 200)
    __syncthreads();

    // per-lane h chunk assignment: lanes 0-12 -> batch0 chunks, 13-25 -> batch1
    const int lane = tid & 63;
    int l = lane;
    if (l >= 26) l -= 26;
    if (l >= 26) l -= 26;
    const int rb = (l < 13) ? 0 : 1;
    const int ch = (l < 13) ? l : (l - 13);

    const float LOG2E = 1.4426950408889634f;

    for (int t = 0; t <= T_LEN; ++t) {
        const int cur = t & 1;   // hbuf[cur] holds h_{t-1}

        // ---- Phase A: one LDS read per lane, readlane-broadcast, dot2 ----
        const uint4 q = *((const uint4*)&hbuf[cur][rb][8 * ch]);

        // x-projection via wave-uniform (scalar) loads
        const int tt = (t < T_LEN) ? t : (T_LEN - 1);
        const float* xr0 = x + ((size_t)b0       * T_LEN + tt) * DIN;
        const float* xr1 = x + ((size_t)(b0 + 1) * T_LEN + tt) * DIN;
        float xgA0 = biasA, xgA1 = biasA, xgB0 = biasB, xgB1 = biasB;
#pragma unroll
        for (int d = 0; d < DIN; ++d) {
            const float xv0 = xr0[d];
            const float xv1 = xr1[d];
            xgA0 += xv0 * wxA[d];
            xgA1 += xv1 * wxA[d];
            xgB0 += xv0 * wxB[d];
            xgB1 += xv1 * wxB[d];
        }

        float zA0 = 0.f, zA1 = 0.f, zB0 = 0.f, zB1 = 0.f;
        const int qx = (int)q.x, qy = (int)q.y, qz = (int)q.z, qw = (int)q.w;
#pragma unroll
        for (int cc = 0; cc < NCH; ++cc) {
            const unsigned int u0x = (unsigned int)__builtin_amdgcn_readlane(qx, cc);
            const unsigned int u0y = (unsigned int)__builtin_amdgcn_readlane(qy, cc);
            const unsigned int u0z = (unsigned int)__builtin_amdgcn_readlane(qz, cc);
            const unsigned int u0w = (unsigned int)__builtin_amdgcn_readlane(qw, cc);
            const unsigned int u1x = (unsigned int)__builtin_amdgcn_readlane(qx, 13 + cc);
            const unsigned int u1y = (unsigned int)__builtin_amdgcn_readlane(qy, 13 + cc);
            const unsigned int u1z = (unsigned int)__builtin_amdgcn_readlane(qz, 13 + cc);
            const unsigned int u1w = (unsigned int)__builtin_amdgcn_readlane(qw, 13 + cc);
            const int p = 4 * cc;
            zA0 = dot2p(u0x, wA[p    ], zA0);
            zA1 = dot2p(u1x, wA[p    ], zA1);
            zB0 = dot2p(u0x, wB[p    ], zB0);
            zB1 = dot2p(u1x, wB[p    ], zB1);
            zA0 = dot2p(u0y, wA[p + 1], zA0);
            zA1 = dot2p(u1y, wA[p + 1], zA1);
            zB0 = dot2p(u0y, wB[p + 1], zB0);
            zB1 = dot2p(u1y, wB[p + 1], zB1);
            zA0 = dot2p(u0z, wA[p + 2], zA0);
            zA1 = dot2p(u1z, wA[p + 2], zA1);
            zB0 = dot2p(u0z, wB[p + 2], zB0);
            zB1 = dot2p(u1z, wB[p + 2], zB1);
            zA0 = dot2p(u0w, wA[p + 3], zA0);
            zA1 = dot2p(u1w, wA[p + 3], zA1);
            zB0 = dot2p(u0w, wB[p + 3], zB0);
            zB1 = dot2p(u1w, wB[p + 3], zB1);
        }
        zA0 += xgA0; zA1 += xgA1; zB0 += xgB0; zB1 += xgB1;

        if (is_mm) {
            if (t < T_LEN) {
                // activations: sigmoid, or tanh(z)=2*sigmoid(2z)-1 for g-columns
                float sA0, sA1, sB0, sB1;
                {
                    const float xs = gA ? 2.f * zA0 : zA0;
                    sA0 = fast_rcp(1.f + fast_exp2(-LOG2E * xs));
                    if (gA) sA0 = 2.f * sA0 - 1.f;
                }
                {
                    const float xs = gA ? 2.f * zA1 : zA1;
                    sA1 = fast_rcp(1.f + fast_exp2(-LOG2E * xs));
                    if (gA) sA1 = 2.f * sA1 - 1.f;
                }
                {
                    const float xs = gB ? 2.f * zB0 : zB0;
                    sB0 = fast_rcp(1.f + fast_exp2(-LOG2E * xs));
                    if (gB) sB0 = 2.f * sB0 - 1.f;
                }
                {
                    const float xs = gB ? 2.f * zB1 : zB1;
                    sB1 = fast_rcp(1.f + fast_exp2(-LOG2E * xs));
                    if (gB) sB1 = 2.f * sB1 - 1.f;
                }
                *((float2*)&za[0][cA]) = make_float2(sA0, sB0);
                *((float2*)&za[1][cA]) = make_float2(sA1, sB1);
            }
        } else if (is_pj) {
            if (t > 0) {
                out[((size_t)b0       * T_LEN + (t - 1)) * DIN + pd] = zA0;
                out[((size_t)(b0 + 1) * T_LEN + (t - 1)) * DIN + pd] = zA1;
            }
        }
        __syncthreads();

        // ---- Phase B: cell update ----
        if (t < T_LEN && tid < 2 * HID) {
            const int r = (tid >= HID) ? 1 : 0;
            const int j = tid - r * HID;
            const float gi = za[r][j];
            const float gf = za[r][HID + j];
            const float gg = za[r][2 * HID + j];
            const float go = za[r][3 * HID + j];
            c = gf * c + gi * gg;
            const float e  = fast_exp2(-2.f * LOG2E * c);
            const float th = 2.f * fast_rcp(1.f + e) - 1.f;
            hbuf[cur ^ 1][r][j] = (__half)(go * th);
        }
        __syncthreads();
    }
}

extern "C" void kernel_launch(void* const* d_in, const int* in_sizes, int n_in,
                              void* d_out, int out_size, void* d_ws, size_t ws_size,
                              hipStream_t stream) {
    const float* x  = (const float*)d_in[0];
    const float* Wx = (const float*)d_in[1];
    const float* Wh = (const float*)d_in[2];
    const float* b  = (const float*)d_in[3];
    const float* Wd = (const float*)d_in[4];
    const float* bd = (const float*)d_in[5];
    float* out = (float*)d_out;

    lstm_fused_kernel<<<BATCH / 2, 256, 0, stream>>>(x, Wx, Wh, b, Wd, bd, out);
}

// Round 3
// 908.755 us; speedup vs baseline: 1.9730x; 1.9730x over previous
//
#include <hip/hip_runtime.h>
#include <math.h>

#define T_LEN 1024
#define BATCH 512
#define DIN   12
#define HID   100
#define G4    400
#define MB    16                 // batches per block
#define NBLK  (BATCH / MB)       // 32 blocks
#define AROW  136                // halves per A row: k=0..127 + 8 pad (272B, 16B-aligned, 2-way-bank-free)

typedef _Float16 half8 __attribute__((ext_vector_type(8)));
typedef float    f32x4 __attribute__((ext_vector_type(4)));

__device__ __forceinline__ float fast_exp2(float v) {
#if __has_builtin(__builtin_amdgcn_exp2f)
    return __builtin_amdgcn_exp2f(v);
#else
    return exp2f(v);
#endif
}
__device__ __forceinline__ float fast_rcp(float v) {
#if __has_builtin(__builtin_amdgcn_rcpf)
    return __builtin_amdgcn_rcpf(v);
#else
    return 1.0f / v;
#endif
}
__device__ __forceinline__ float sigm(float v) {
    return fast_rcp(1.f + fast_exp2(-1.4426950408889634f * v));
}
__device__ __forceinline__ float tanh_f(float v) {
    return 2.f * fast_rcp(1.f + fast_exp2(-2.8853900817779268f * v)) - 1.f;
}

// Block: 512 threads (8 waves), grid: 32 blocks (16 batches each).
// Waves 0-6: j-tile w (j = w*16 + lane&15); each computes ALL FOUR gate columns
//   {G*100+j} via 16 mfma (4 gates x 4 K-tiles) -> activation + cell update in-register.
// Wave 7: output projection (Wd columns) of h_{t-1} + x staging for t+1.
// A (augmented [h | x_t]) lives in LDS, double-buffered by parity; ONE barrier per step.
__launch_bounds__(512, 2)
__global__ void lstm_mfma_kernel(const float* __restrict__ x,
                                 const float* __restrict__ Wx,
                                 const float* __restrict__ Wh,
                                 const float* __restrict__ b,
                                 const float* __restrict__ Wd,
                                 const float* __restrict__ bd,
                                 float* __restrict__ out) {
    __shared__ __align__(16) char smem[65536];

    const int tid  = threadIdx.x;
    const int wid  = tid >> 6;
    const int lane = tid & 63;
    const int l    = lane & 15;
    const int quad = lane >> 4;
    const int b0   = blockIdx.x * MB;

    const int j0 = wid * 16;
    const int j  = j0 + l;          // gate row index for waves 0-6 (valid if j < 100)

    // ---- Stage B fragments through LDS so the allocator cannot sink the loads
    //      into the t-loop (ds_read can't move across __syncthreads). ----
    _Float16* stage = (_Float16*)smem;       // [8 waves][8 frags][512 halves] = 64 KB
    half8 bfrag[4][4];                        // [gate][kt]   (waves 0-6)
    half8 bfragP[4];                          // proj [kt]    (wave 7)

#pragma unroll
    for (int pass = 0; pass < 2; ++pass) {
        if (wid < 7) {
#pragma unroll
            for (int gg = 0; gg < 2; ++gg) {
                const int G   = pass * 2 + gg;
                const int col = G * HID + j;
#pragma unroll
                for (int kt = 0; kt < 4; ++kt) {
                    half8 v;
#pragma unroll
                    for (int jj = 0; jj < 8; ++jj) {
                        const int k = kt * 32 + quad * 8 + jj;
                        float w = 0.f;
                        if (j < HID) {
                            if (k < HID)            w = Wh[k * G4 + col];
                            else if (k < HID + DIN) w = Wx[(k - HID) * G4 + col];
                        }
                        v[jj] = (_Float16)w;
                    }
                    *(half8*)&stage[((wid * 8) + (gg * 4 + kt)) * 512 + lane * 8] = v;
                }
            }
        } else if (pass == 0) {
#pragma unroll
            for (int kt = 0; kt < 4; ++kt) {
                half8 v;
#pragma unroll
                for (int jj = 0; jj < 8; ++jj) {
                    const int k = kt * 32 + quad * 8 + jj;
                    float w = 0.f;
                    if (l < DIN && k < HID) w = Wd[k * DIN + l];
                    v[jj] = (_Float16)w;
                }
                *(half8*)&stage[(7 * 8 + kt) * 512 + lane * 8] = v;
            }
        }
        __syncthreads();
        if (wid < 7) {
#pragma unroll
            for (int gg = 0; gg < 2; ++gg)
#pragma unroll
                for (int kt = 0; kt < 4; ++kt)
                    bfrag[pass * 2 + gg][kt] =
                        *(half8*)&stage[((wid * 8) + (gg * 4 + kt)) * 512 + lane * 8];
        } else if (pass == 0) {
#pragma unroll
            for (int kt = 0; kt < 4; ++kt)
                bfragP[kt] = *(half8*)&stage[(7 * 8 + kt) * 512 + lane * 8];
        }
        __syncthreads();
    }

    // per-lane biases
    float biasv[4];
#pragma unroll
    for (int G = 0; G < 4; ++G)
        biasv[G] = (wid < 7 && j < HID) ? b[G * HID + j] : 0.f;
    const float bdv = (l < DIN) ? bd[l] : 0.f;

    // ---- A buffer: [parity][m=0..15][k halves 0..135], h in k=0..99, x in 100..111 ----
    _Float16 (*Ah)[MB][AROW] = (_Float16 (*)[MB][AROW])smem;   // 2*16*136*2 = 8704 B
    for (int i = tid; i < 2 * MB * AROW / 2; i += 512) ((int*)smem)[i] = 0;
    __syncthreads();
    if (tid < MB * DIN) {
        const int m = tid / DIN, d = tid - m * DIN;
        Ah[0][m][HID + d] = (_Float16)x[((size_t)(b0 + m) * T_LEN + 0) * DIN + d];
    }
    __syncthreads();

    f32x4 c4 = {0.f, 0.f, 0.f, 0.f};   // cell state: rows m=quad*4+r for this lane's j

#pragma unroll 1
    for (int t = 0; t <= T_LEN; ++t) {
        const int p  = t & 1;
        const int pn = p ^ 1;

        // A fragments (all waves need them)
        half8 a[4];
#pragma unroll
        for (int kt = 0; kt < 4; ++kt)
            a[kt] = *(const half8*)&Ah[p][l][kt * 32 + quad * 8];

        if (wid < 7) {
            f32x4 acc[4];
#pragma unroll
            for (int G = 0; G < 4; ++G) {
                const float bv = biasv[G];
                acc[G] = (f32x4){bv, bv, bv, bv};
            }
#pragma unroll
            for (int G = 0; G < 4; ++G)
#pragma unroll
                for (int kt = 0; kt < 4; ++kt)
                    acc[G] = __builtin_amdgcn_mfma_f32_16x16x32_f16(a[kt], bfrag[G][kt], acc[G], 0, 0, 0);

            // activation + cell update, fully in-register (gate order: i, f, g, o)
            f32x4 hi;
#pragma unroll
            for (int r = 0; r < 4; ++r) {
                const float gi = sigm(acc[0][r]);
                const float gf = sigm(acc[1][r]);
                const float gg = tanh_f(acc[2][r]);
                const float go = sigm(acc[3][r]);
                const float cn = gf * c4[r] + gi * gg;
                c4[r] = cn;
                hi[r] = go * tanh_f(cn);
            }
            if (j < HID && t < T_LEN) {
#pragma unroll
                for (int r = 0; r < 4; ++r)
                    Ah[pn][quad * 4 + r][j] = (_Float16)hi[r];
            }
        } else {
            // x prefetch for t+1 (issue loads early)
            const int tt = (t + 1 < T_LEN) ? (t + 1) : (T_LEN - 1);
            float xv[3];
            int   xm[3], xd[3];
#pragma unroll
            for (int ii = 0; ii < 3; ++ii) {
                const int idx = lane + 64 * ii;          // 0..191
                xm[ii] = idx / DIN;
                xd[ii] = idx - xm[ii] * DIN;
                xv[ii] = x[((size_t)(b0 + xm[ii]) * T_LEN + tt) * DIN + xd[ii]];
            }

            f32x4 accP = {bdv, bdv, bdv, bdv};
#pragma unroll
            for (int kt = 0; kt < 4; ++kt)
                accP = __builtin_amdgcn_mfma_f32_16x16x32_f16(a[kt], bfragP[kt], accP, 0, 0, 0);

            if (t > 0 && l < DIN) {
#pragma unroll
                for (int r = 0; r < 4; ++r)
                    out[((size_t)(b0 + quad * 4 + r) * T_LEN + (t - 1)) * DIN + l] = accP[r];
            }
            // stage x_{t+1} into the other parity buffer
#pragma unroll
            for (int ii = 0; ii < 3; ++ii)
                Ah[pn][xm[ii]][HID + xd[ii]] = (_Float16)xv[ii];
        }
        __syncthreads();
    }
}

extern "C" void kernel_launch(void* const* d_in, const int* in_sizes, int n_in,
                              void* d_out, int out_size, void* d_ws, size_t ws_size,
                              hipStream_t stream) {
    const float* x  = (const float*)d_in[0];
    const float* Wx = (const float*)d_in[1];
    const float* Wh = (const float*)d_in[2];
    const float* b  = (const float*)d_in[3];
    const float* Wd = (const float*)d_in[4];
    const float* bd = (const float*)d_in[5];
    float* out = (float*)d_out;

    lstm_mfma_kernel<<<NBLK, 512, 0, stream>>>(x, Wx, Wh, b, Wd, bd, out);
}